// Round 2
// baseline (1760.585 us; speedup 1.0000x reference)
//
#include <hip/hip_runtime.h>

// ---------------------------------------------------------------------------
// Double attention model, f32 baseline (round 1 resubmit — round 1 bench was
// a GPU-acquisition timeout, no signal).
//   B=64 S=32 N=64 E=128 H=4 D=32
// Algebraic fusions:
//   * T (=ctx1@tWo^T+tbo) folded into stage-2 K/V projections:
//       Wk' = sWk@tWo, bk' = sWk@tbo + sbk  (same for V)  -> T never formed.
//   * stage-2 softmax computed ONLINE per (n,b) -> ks/vs never materialized.
// Workspace: kt,vt (64MB each) + qt,qs (2MB each) + folded weights ~= 132MB.
// ---------------------------------------------------------------------------

constexpr int Bb = 64, Ss = 32, Nn = 64, Ee = 128, Hh = 4, Dd = 32;
constexpr int TB = 256;
constexpr int LD = 132;  // padded LDS row stride (breaks stride-128 bank conflicts)
constexpr float SCALE = 0.17677669529663687f;  // 1/sqrt(32)

__device__ __forceinline__ float4 f4_load(const float* p) {
  return *reinterpret_cast<const float4*>(p);
}
__device__ __forceinline__ void f4_store(float* p, float4 v) {
  *reinterpret_cast<float4*>(p) = v;
}

// ---------------- fold stage-2 K/V weights through t_Wo ----------------
// Wp[i][j] = sum_k sW[i][k] * tWo[k][j];  bp[i] = sum_k sW[i][k]*tbo[k] + sb[i]
__global__ __launch_bounds__(128) void fuse_weights_kernel(
    const float* __restrict__ sWk, const float* __restrict__ sbk,
    const float* __restrict__ sWv, const float* __restrict__ sbv,
    const float* __restrict__ tWo, const float* __restrict__ tbo,
    float* __restrict__ Wkp, float* __restrict__ bkp,
    float* __restrict__ Wvp, float* __restrict__ bvp) {
  const int i = blockIdx.x;
  const int which = blockIdx.y;
  const float* sW = which ? sWv : sWk;
  const float* sb = which ? sbv : sbk;
  float* Wp = which ? Wvp : Wkp;
  float* bp = which ? bvp : bkp;
  __shared__ float srow[Ee];
  const int t = threadIdx.x;
  srow[t] = sW[i * Ee + t];
  __syncthreads();
  float acc = 0.f;
  for (int k = 0; k < Ee; ++k) acc += srow[k] * tWo[k * Ee + t];
  Wp[i * Ee + t] = acc;
  if (t == 0) {
    float bb = sb[i];
    for (int k = 0; k < Ee; ++k) bb += srow[k] * tbo[k];
    bp[i] = bb;
  }
}

// ---------------- q projections: qt = q@tWq^T+tbq, qs = q@sWq^T+sbq --------
// grid (B, 2); q = x[b, S-1, n, :]
__global__ __launch_bounds__(256) void qproj_kernel(
    const float* __restrict__ x,
    const float* __restrict__ tWq, const float* __restrict__ tbq,
    const float* __restrict__ sWq, const float* __restrict__ sbq,
    float* __restrict__ qt_ws, float* __restrict__ qs_ws) {
  extern __shared__ float lds[];
  float* q_l = lds;             // [64][128]
  float* W_l = lds + 64 * Ee;   // transposed [k][e]
  const int b = blockIdx.x;
  const int which = blockIdx.y;
  const float* W = which ? sWq : tWq;
  const float* bias = which ? sbq : tbq;
  float* outp = which ? qs_ws : qt_ws;
  const int t = threadIdx.x;
  for (int idx = t; idx < 64 * Ee; idx += TB) {
    int n = idx >> 7, e = idx & 127;
    q_l[idx] = x[(((size_t)b * Ss + (Ss - 1)) * Nn + n) * Ee + e];
  }
  for (int idx = t; idx < Ee * Ee / 4; idx += TB) {
    int e = idx >> 5, k0 = (idx & 31) << 2;
    float4 w = f4_load(&W[e * Ee + k0]);
    W_l[(k0 + 0) * Ee + e] = w.x;
    W_l[(k0 + 1) * Ee + e] = w.y;
    W_l[(k0 + 2) * Ee + e] = w.z;
    W_l[(k0 + 3) * Ee + e] = w.w;
  }
  __syncthreads();
  const int ngrp = t >> 5;           // 0..7 -> 8 n rows each
  const int e0 = (t & 31) << 2;      // 4 e cols
  float acc[8][4];
#pragma unroll
  for (int j = 0; j < 8; ++j)
#pragma unroll
    for (int c = 0; c < 4; ++c) acc[j][c] = 0.f;
  for (int k = 0; k < Ee; ++k) {
    float4 w = f4_load(&W_l[k * Ee + e0]);
#pragma unroll
    for (int j = 0; j < 8; ++j) {
      float a = q_l[(ngrp * 8 + j) * Ee + k];
      acc[j][0] += a * w.x; acc[j][1] += a * w.y;
      acc[j][2] += a * w.z; acc[j][3] += a * w.w;
    }
  }
  float4 bb = f4_load(&bias[e0]);
#pragma unroll
  for (int j = 0; j < 8; ++j) {
    int n = ngrp * 8 + j;
    float4 o;
    o.x = acc[j][0] + bb.x; o.y = acc[j][1] + bb.y;
    o.z = acc[j][2] + bb.z; o.w = acc[j][3] + bb.w;
    f4_store(&outp[((size_t)b * Nn + n) * Ee + e0], o);
  }
}

// ---------------- kt/vt projection: [b][n][s][e] layout --------------------
// grid (B, 8): block handles 8 n's; weights staged one at a time (80KB LDS,
// 2 blocks/CU).
__global__ __launch_bounds__(256) void ktvt_kernel(
    const float* __restrict__ x,
    const float* __restrict__ tWk, const float* __restrict__ tbk,
    const float* __restrict__ tWv, const float* __restrict__ tbv,
    float* __restrict__ kt_ws, float* __restrict__ vt_ws) {
  extern __shared__ float lds[];
  float* W_l = lds;              // transposed [k][e] 128x128
  float* x_l = lds + Ee * Ee;    // [s][k] 32x128
  const int b = blockIdx.x;
  const int n0 = blockIdx.y * 8;
  const int t = threadIdx.x;
  const int s0 = (t >> 5) << 2;
  const int e0 = (t & 31) << 2;
  for (int mat = 0; mat < 2; ++mat) {
    const float* Wg = mat ? tWv : tWk;
    const float* bg = mat ? tbv : tbk;
    float* og = mat ? vt_ws : kt_ws;
    __syncthreads();  // previous pass done with W_l / x_l
    for (int idx = t; idx < Ee * Ee / 4; idx += TB) {
      int e = idx >> 5, k0 = (idx & 31) << 2;
      float4 w = f4_load(&Wg[e * Ee + k0]);
      W_l[(k0 + 0) * Ee + e] = w.x;
      W_l[(k0 + 1) * Ee + e] = w.y;
      W_l[(k0 + 2) * Ee + e] = w.z;
      W_l[(k0 + 3) * Ee + e] = w.w;
    }
    float4 bb = f4_load(&bg[e0]);
    for (int ni = 0; ni < 8; ++ni) {
      const int n = n0 + ni;
      __syncthreads();
      for (int idx = t; idx < Ss * Ee / 4; idx += TB) {
        int s = idx >> 5, k4 = (idx & 31) << 2;
        f4_store(&x_l[s * Ee + k4],
                 f4_load(&x[(((size_t)b * Ss + s) * Nn + n) * Ee + k4]));
      }
      __syncthreads();
      float acc[4][4];
#pragma unroll
      for (int j = 0; j < 4; ++j)
#pragma unroll
        for (int c = 0; c < 4; ++c) acc[j][c] = 0.f;
      for (int k = 0; k < Ee; ++k) {
        float4 w = f4_load(&W_l[k * Ee + e0]);
#pragma unroll
        for (int j = 0; j < 4; ++j) {
          float a = x_l[(s0 + j) * Ee + k];
          acc[j][0] += a * w.x; acc[j][1] += a * w.y;
          acc[j][2] += a * w.z; acc[j][3] += a * w.w;
        }
      }
#pragma unroll
      for (int j = 0; j < 4; ++j) {
        const size_t base = (((size_t)b * Nn + n) * Ss + (s0 + j)) * Ee + e0;
        float4 o;
        o.x = acc[j][0] + bb.x; o.y = acc[j][1] + bb.y;
        o.z = acc[j][2] + bb.z; o.w = acc[j][3] + bb.w;
        f4_store(&og[base], o);
      }
    }
  }
}

// ---------------- chunk GEMM helper: (32 x 128) @ Wg^T + bg -> kvc ---------
__device__ __forceinline__ void chunk_gemm(const float* __restrict__ Wg,
                                           const float* __restrict__ bg,
                                           const float* ctx1, float* Wt,
                                           float* kvc, int t) {
  const int ge0 = (t & 15) * 8;
  const int gr0 = (t >> 4) * 2;
  float acc[2][8];
#pragma unroll
  for (int r = 0; r < 2; ++r)
#pragma unroll
    for (int j = 0; j < 8; ++j) acc[r][j] = 0.f;
  for (int k0 = 0; k0 < Ee; k0 += 32) {
    for (int idx = t; idx < 1024; idx += TB) {
      int e = idx >> 3, kk0 = (idx & 7) << 2;
      float4 w = f4_load(&Wg[e * Ee + k0 + kk0]);
      Wt[(kk0 + 0) * Ee + e] = w.x;
      Wt[(kk0 + 1) * Ee + e] = w.y;
      Wt[(kk0 + 2) * Ee + e] = w.z;
      Wt[(kk0 + 3) * Ee + e] = w.w;
    }
    __syncthreads();
#pragma unroll
    for (int kk = 0; kk < 32; ++kk) {
      float a0 = ctx1[(gr0 + 0) * LD + k0 + kk];
      float a1 = ctx1[(gr0 + 1) * LD + k0 + kk];
      float4 w0 = f4_load(&Wt[kk * Ee + ge0]);
      float4 w1 = f4_load(&Wt[kk * Ee + ge0 + 4]);
      acc[0][0] += a0 * w0.x; acc[0][1] += a0 * w0.y;
      acc[0][2] += a0 * w0.z; acc[0][3] += a0 * w0.w;
      acc[0][4] += a0 * w1.x; acc[0][5] += a0 * w1.y;
      acc[0][6] += a0 * w1.z; acc[0][7] += a0 * w1.w;
      acc[1][0] += a1 * w0.x; acc[1][1] += a1 * w0.y;
      acc[1][2] += a1 * w0.z; acc[1][3] += a1 * w0.w;
      acc[1][4] += a1 * w1.x; acc[1][5] += a1 * w1.y;
      acc[1][6] += a1 * w1.z; acc[1][7] += a1 * w1.w;
    }
    __syncthreads();
  }
#pragma unroll
  for (int r = 0; r < 2; ++r)
#pragma unroll
    for (int j = 0; j < 8; ++j)
      kvc[(gr0 + r) * LD + ge0 + j] = acc[r][j] + bg[ge0 + j];
}

// ---------------- main fused kernel: grid (8 n-chunks, 64 b) ---------------
__global__ __launch_bounds__(256) void main_kernel(
    const float* __restrict__ kt_ws, const float* __restrict__ vt_ws,
    const float* __restrict__ qt_ws, const float* __restrict__ qs_ws,
    const float* __restrict__ Wkp, const float* __restrict__ bkp,
    const float* __restrict__ Wvp, const float* __restrict__ bvp,
    const float* __restrict__ sWo, const float* __restrict__ sbo,
    const int* __restrict__ adj, float* __restrict__ out) {
  extern __shared__ float lds[];
  float* qt_l = lds;                    // [8][128]
  float* qs_l = lds + 1024;             // [8][128]
  float* p_l = lds + 2048;              // [8][4][32] stage-1 probs
  float* sc2_l = lds + 3072;            // [8][4][4]
  float* w2_l = lds + 3200;             // [8][4][4]
  float* r_l = lds + 3328;              // [8][4]
  float* M_l = lds + 3360;              // [8][4]
  float* L_l = lds + 3392;              // [8][4]
  float* kv_m = lds + 3424;             // [32][LD] kt/vt slice
  float* ctx1 = lds + 3424 + 32 * LD;   // [32][LD], later ctx2 [8][LD]
  float* kvc = lds + 3424 + 2 * 32 * LD;   // [32][LD] ks then vs
  float* Wt = lds + 3424 + 3 * 32 * LD;    // [32][128] weight k-tile

  const int n0 = blockIdx.x * 8;
  const int b = blockIdx.y;
  const int t = threadIdx.x;

  for (int idx = t; idx < 1024; idx += TB) {
    int i = idx >> 7, e = idx & 127;
    qt_l[idx] = qt_ws[((size_t)b * Nn + n0 + i) * Ee + e];
    qs_l[idx] = qs_ws[((size_t)b * Nn + n0 + i) * Ee + e];
  }
  if (t < 32) { M_l[t] = -1e30f; L_l[t] = 0.f; }
  // ctx2 accumulator lives in registers: thread -> (i, h, d0..d0+3)
  const int ci = t >> 5, ch = (t >> 3) & 3, cd0 = (t & 7) << 2;
  float c0 = 0.f, c1 = 0.f, c2 = 0.f, c3 = 0.f;
  __syncthreads();

  for (int m0 = 0; m0 < Nn; m0 += 4) {
    // ---- stage 1: build ctx1 rows (mc*8+i) for 4 m's ----
    for (int mc = 0; mc < 4; ++mc) {
      const int m = m0 + mc;
      const size_t kvbase = (((size_t)b * Nn + m) * Ss) * Ee;
      for (int idx = t; idx < Ss * Ee / 4; idx += TB) {
        int s = idx >> 5, e4 = (idx & 31) << 2;
        f4_store(&kv_m[s * LD + e4], f4_load(&kt_ws[kvbase + s * Ee + e4]));
      }
      __syncthreads();
      {  // scores: thread (i = t>>5, s = t&31), loop h
        const int i = t >> 5, s = t & 31;
#pragma unroll
        for (int h = 0; h < Hh; ++h) {
          float acc = 0.f;
#pragma unroll
          for (int d0 = 0; d0 < Dd; d0 += 4) {
            float4 a = f4_load(&qt_l[i * Ee + h * Dd + d0]);
            float4 kk4 = f4_load(&kv_m[s * LD + h * Dd + d0]);
            acc += a.x * kk4.x + a.y * kk4.y + a.z * kk4.z + a.w * kk4.w;
          }
          p_l[(i * Hh + h) * Ss + s] = acc * SCALE;
        }
      }
      __syncthreads();
      if (t < 32) {  // softmax over s per (i,h)
        float* row = &p_l[t * Ss];
        float mx = row[0];
        for (int s2 = 1; s2 < Ss; ++s2) mx = fmaxf(mx, row[s2]);
        float sum = 0.f;
        for (int s2 = 0; s2 < Ss; ++s2) {
          float w = __expf(row[s2] - mx);
          row[s2] = w;
          sum += w;
        }
        float inv = 1.f / sum;
        for (int s2 = 0; s2 < Ss; ++s2) row[s2] *= inv;
      }
      __syncthreads();
      for (int idx = t; idx < Ss * Ee / 4; idx += TB) {  // stage vt
        int s = idx >> 5, e4 = (idx & 31) << 2;
        f4_store(&kv_m[s * LD + e4], f4_load(&vt_ws[kvbase + s * Ee + e4]));
      }
      __syncthreads();
      {  // ctx1 row: thread (i, e0)
        const int i = t >> 5;
        const int e0 = (t & 31) << 2;
        const float* prow = &p_l[(i * Hh + (e0 >> 5)) * Ss];
        float ax = 0.f, ay = 0.f, az = 0.f, aw = 0.f;
        for (int s2 = 0; s2 < Ss; ++s2) {
          float w = prow[s2];
          float4 v = f4_load(&kv_m[s2 * LD + e0]);
          ax += w * v.x; ay += w * v.y; az += w * v.z; aw += w * v.w;
        }
        float4 o; o.x = ax; o.y = ay; o.z = az; o.w = aw;
        f4_store(&ctx1[(mc * 8 + i) * LD + e0], o);
      }
      __syncthreads();
    }
    // ---- ks = ctx1 @ Wk'^T + bk' ----
    chunk_gemm(Wkp, bkp, ctx1, Wt, kvc, t);
    __syncthreads();
    // ---- stage-2 masked scores ----
    if (t < 128) {
      const int i = t >> 4, h = (t >> 2) & 3, mc = t & 3;
      const int m = m0 + mc;
      float sc = -1e30f;
      if (adj[(n0 + i) * Nn + m] > 0) {
        float acc = 0.f;
#pragma unroll
        for (int d0 = 0; d0 < Dd; d0 += 4) {
          float4 a = f4_load(&qs_l[i * Ee + h * Dd + d0]);
          float4 kk4 = f4_load(&kvc[(mc * 8 + i) * LD + h * Dd + d0]);
          acc += a.x * kk4.x + a.y * kk4.y + a.z * kk4.z + a.w * kk4.w;
        }
        sc = acc * SCALE;
      }
      sc2_l[t] = sc;
    }
    __syncthreads();
    // ---- online softmax bookkeeping (t<32 ~ (i,h)) ----
    if (t < 32) {
      float Mo = M_l[t];
      const float* srow = &sc2_l[t * 4];
      float mx = Mo;
#pragma unroll
      for (int mc = 0; mc < 4; ++mc) mx = fmaxf(mx, srow[mc]);
      float r = __expf(Mo - mx);
      float sw = 0.f;
#pragma unroll
      for (int mc = 0; mc < 4; ++mc) {
        float v = srow[mc];
        float w = (v < -1e29f) ? 0.f : __expf(v - mx);
        w2_l[t * 4 + mc] = w;
        sw += w;
      }
      M_l[t] = mx;
      L_l[t] = L_l[t] * r + sw;
      r_l[t] = r;
    }
    // ---- vs = ctx1 @ Wv'^T + bv' (internal syncs order everything) ----
    chunk_gemm(Wvp, bvp, ctx1, Wt, kvc, t);
    __syncthreads();
    // ---- ctx2 online accumulate ----
    {
      float r = r_l[ci * 4 + ch];
      const float* wrow = &w2_l[(ci * 4 + ch) * 4];
      float ax = 0.f, ay = 0.f, az = 0.f, aw = 0.f;
#pragma unroll
      for (int mc = 0; mc < 4; ++mc) {
        float w = wrow[mc];
        float4 v = f4_load(&kvc[(mc * 8 + ci) * LD + ch * Dd + cd0]);
        ax += w * v.x; ay += w * v.y; az += w * v.z; aw += w * v.w;
      }
      c0 = c0 * r + ax; c1 = c1 * r + ay;
      c2 = c2 * r + az; c3 = c3 * r + aw;
    }
    __syncthreads();
  }
  // ---- finalize ctx2 -> LDS (reuse ctx1 region) ----
  {
    float invL = 1.f / L_l[ci * 4 + ch];
    float* ctx2_l = ctx1;
    ctx2_l[ci * LD + ch * Dd + cd0 + 0] = c0 * invL;
    ctx2_l[ci * LD + ch * Dd + cd0 + 1] = c1 * invL;
    ctx2_l[ci * LD + ch * Dd + cd0 + 2] = c2 * invL;
    ctx2_l[ci * LD + ch * Dd + cd0 + 3] = c3 * invL;
  }
  __syncthreads();
  // ---- output projection: out[b,n,:] = ctx2 @ sWo^T + sbo ----
  {
    const int i = t >> 5, e0 = (t & 31) << 2;
    float ax = 0.f, ay = 0.f, az = 0.f, aw = 0.f;
    for (int k0 = 0; k0 < Ee; k0 += 32) {
      for (int idx = t; idx < 1024; idx += TB) {
        int e = idx >> 3, kk0 = (idx & 7) << 2;
        float4 w = f4_load(&sWo[e * Ee + k0 + kk0]);
        Wt[(kk0 + 0) * Ee + e] = w.x;
        Wt[(kk0 + 1) * Ee + e] = w.y;
        Wt[(kk0 + 2) * Ee + e] = w.z;
        Wt[(kk0 + 3) * Ee + e] = w.w;
      }
      __syncthreads();
#pragma unroll
      for (int kk = 0; kk < 32; ++kk) {
        float a = ctx1[i * LD + k0 + kk];
        float4 w = f4_load(&Wt[kk * Ee + e0]);
        ax += a * w.x; ay += a * w.y; az += a * w.z; aw += a * w.w;
      }
      __syncthreads();
    }
    float4 bb = f4_load(&sbo[e0]);
    float4 o;
    o.x = ax + bb.x; o.y = ay + bb.y; o.z = az + bb.z; o.w = aw + bb.w;
    f4_store(&out[((size_t)b * Nn + n0 + i) * Ee + e0], o);
  }
}

// ---------------------------------------------------------------------------
extern "C" void kernel_launch(void* const* d_in, const int* in_sizes, int n_in,
                              void* d_out, int out_size, void* d_ws,
                              size_t ws_size, hipStream_t stream) {
  const float* x = (const float*)d_in[0];
  const int* adj = (const int*)d_in[1];
  const float* tWq = (const float*)d_in[2];
  const float* tbq = (const float*)d_in[3];
  const float* tWk = (const float*)d_in[4];
  const float* tbk = (const float*)d_in[5];
  const float* tWv = (const float*)d_in[6];
  const float* tbv = (const float*)d_in[7];
  const float* tWo = (const float*)d_in[8];
  const float* tbo = (const float*)d_in[9];
  const float* sWq = (const float*)d_in[10];
  const float* sbq = (const float*)d_in[11];
  const float* sWk = (const float*)d_in[12];
  const float* sbk = (const float*)d_in[13];
  const float* sWv = (const float*)d_in[14];
  const float* sbv = (const float*)d_in[15];
  const float* sWo = (const float*)d_in[16];
  const float* sbo = (const float*)d_in[17];
  float* out = (float*)d_out;

  float* ws = (float*)d_ws;
  const size_t ktvt_elems = (size_t)Bb * Nn * Ss * Ee;  // 16,777,216
  const size_t q_elems = (size_t)Bb * Nn * Ee;          // 524,288
  float* kt_ws = ws;
  float* vt_ws = kt_ws + ktvt_elems;
  float* qt_ws = vt_ws + ktvt_elems;
  float* qs_ws = qt_ws + q_elems;
  float* Wkp = qs_ws + q_elems;
  float* Wvp = Wkp + Ee * Ee;
  float* bkp = Wvp + Ee * Ee;
  float* bvp = bkp + Ee;

  const int qproj_lds = (64 * Ee + Ee * Ee) * 4;           // 96 KB
  const int ktvt_lds = (Ee * Ee + Ss * Ee) * 4;            // 80 KB
  const int main_lds = (3424 + 3 * 32 * LD + 32 * Ee) * 4; // ~79 KB
  (void)hipFuncSetAttribute((const void*)qproj_kernel,
                            hipFuncAttributeMaxDynamicSharedMemorySize,
                            qproj_lds);
  (void)hipFuncSetAttribute((const void*)ktvt_kernel,
                            hipFuncAttributeMaxDynamicSharedMemorySize,
                            ktvt_lds);
  (void)hipFuncSetAttribute((const void*)main_kernel,
                            hipFuncAttributeMaxDynamicSharedMemorySize,
                            main_lds);

  fuse_weights_kernel<<<dim3(Ee, 2), 128, 0, stream>>>(
      sWk, sbk, sWv, sbv, tWo, tbo, Wkp, bkp, Wvp, bvp);
  qproj_kernel<<<dim3(Bb, 2), TB, qproj_lds, stream>>>(x, tWq, tbq, sWq, sbq,
                                                       qt_ws, qs_ws);
  ktvt_kernel<<<dim3(Bb, 8), TB, ktvt_lds, stream>>>(x, tWk, tbk, tWv, tbv,
                                                     kt_ws, vt_ws);
  main_kernel<<<dim3(8, Bb), TB, main_lds, stream>>>(
      kt_ws, vt_ws, qt_ws, qs_ws, Wkp, bkp, Wvp, bvp, sWo, sbo, adj, out);
}

// Round 4
// 762.335 us; speedup vs baseline: 2.3095x; 2.3095x over previous
//
#include <hip/hip_runtime.h>

// ---------------------------------------------------------------------------
// Double attention, round 4: f32. Round-3 structure + ONE fix:
//   stage-2 score reduction now contracts the FULL e range per head
//   (round 3 wrongly summed only each head's diagonal 32-wide e-block).
//   B=64 S=32 N=64 E=128 H=4 D=32
// ---------------------------------------------------------------------------

constexpr int Bb = 64, Ss = 32, Nn = 64, Ee = 128, Hh = 4, Dd = 32;
constexpr int MS = 2;                       // m-split factor
constexpr float SCALE = 0.17677669529663687f;  // 1/sqrt(32)

__device__ __forceinline__ float4 f4_load(const float* p) {
  return *reinterpret_cast<const float4*>(p);
}
__device__ __forceinline__ void f4_store(float* p, float4 v) {
  *reinterpret_cast<float4*>(p) = v;
}
__device__ __forceinline__ float dot4(float4 a, float4 b) {
  return a.x * b.x + a.y * b.y + a.z * b.z + a.w * b.w;
}

// ---------------- fold stage-2 K/V weights through t_Wo --------------------
__global__ __launch_bounds__(128) void fuse_weights_kernel(
    const float* __restrict__ sWk, const float* __restrict__ sbk,
    const float* __restrict__ sWv, const float* __restrict__ sbv,
    const float* __restrict__ tWo, const float* __restrict__ tbo,
    float* __restrict__ Wkp, float* __restrict__ bkp,
    float* __restrict__ Wvp, float* __restrict__ bvp) {
  const int i = blockIdx.x;
  const int which = blockIdx.y;
  const float* sW = which ? sWv : sWk;
  const float* sb = which ? sbv : sbk;
  float* Wp = which ? Wvp : Wkp;
  float* bp = which ? bvp : bkp;
  __shared__ float srow[Ee];
  const int t = threadIdx.x;
  srow[t] = sW[i * Ee + t];
  __syncthreads();
  float acc = 0.f;
  for (int k = 0; k < Ee; ++k) acc += srow[k] * tWo[k * Ee + t];
  Wp[i * Ee + t] = acc;
  if (t == 0) {
    float bb = sb[i];
    for (int k = 0; k < Ee; ++k) bb += srow[k] * tbo[k];
    bp[i] = bb;
  }
}

// ---------------- q projections + qk2/qb2 ----------------------------------
// grid (B, 2). which=0: qt = q@tWq^T+tbq -> qt_ws.
// which=1: qs = q@sWq^T+sbq (kept in LDS), then
//   qk2[n,h,e] = sum_d qs[n,hD+d]*Wk'[hD+d][e], qb2[n,h] = sum_d qs*bk'.
__global__ __launch_bounds__(256) void qproj_kernel(
    const float* __restrict__ x,
    const float* __restrict__ tWq, const float* __restrict__ tbq,
    const float* __restrict__ sWq, const float* __restrict__ sbq,
    const float* __restrict__ Wkp, const float* __restrict__ bkp,
    float* __restrict__ qt_ws, float* __restrict__ qk2_ws,
    float* __restrict__ qb2_ws) {
  __shared__ float q_l[64 * 132];   // [n][132]
  __shared__ float W_l[32 * 128];   // k-quarter, [k][e]
  __shared__ float bk_l[128];
  const int b = blockIdx.x;
  const int which = blockIdx.y;
  const float* W = which ? sWq : tWq;
  const float* bias = which ? sbq : tbq;
  const int t = threadIdx.x;
  // stage q rows (x[b, S-1, n, :])
  for (int idx = t; idx < 2048; idx += 256) {
    int nn = idx >> 5, e4 = (idx & 31) << 2;
    f4_store(&q_l[nn * 132 + e4],
             f4_load(&x[(((size_t)b * Ss + (Ss - 1)) * Nn + nn) * Ee + e4]));
  }
  if (which && t < 32) f4_store(&bk_l[t * 4], f4_load(&bkp[t * 4]));

  const int ng = t >> 5;
  const int e0 = (t & 31) << 2;
  float4 acc[8];
#pragma unroll
  for (int j = 0; j < 8; ++j) acc[j] = make_float4(0.f, 0.f, 0.f, 0.f);

  for (int kq = 0; kq < 4; ++kq) {
    __syncthreads();
    // stage W quarter transposed: W_l[k][e] from W[e][kq*32+k]
    for (int idx = t; idx < 1024; idx += 256) {
      int e = idx & 127, k0 = (idx >> 7) << 2;
      float4 w = f4_load(&W[e * Ee + kq * 32 + k0]);
      W_l[(k0 + 0) * 128 + e] = w.x;
      W_l[(k0 + 1) * 128 + e] = w.y;
      W_l[(k0 + 2) * 128 + e] = w.z;
      W_l[(k0 + 3) * 128 + e] = w.w;
    }
    __syncthreads();
#pragma unroll
    for (int j = 0; j < 8; ++j) {
      const int n = ng * 8 + j;
      float4 a = acc[j];
      for (int k0 = 0; k0 < 32; k0 += 4) {
        float4 qv = f4_load(&q_l[n * 132 + kq * 32 + k0]);
        float4 w0 = f4_load(&W_l[(k0 + 0) * 128 + e0]);
        float4 w1 = f4_load(&W_l[(k0 + 1) * 128 + e0]);
        float4 w2 = f4_load(&W_l[(k0 + 2) * 128 + e0]);
        float4 w3 = f4_load(&W_l[(k0 + 3) * 128 + e0]);
        a.x += qv.x * w0.x + qv.y * w1.x + qv.z * w2.x + qv.w * w3.x;
        a.y += qv.x * w0.y + qv.y * w1.y + qv.z * w2.y + qv.w * w3.y;
        a.z += qv.x * w0.z + qv.y * w1.z + qv.z * w2.z + qv.w * w3.z;
        a.w += qv.x * w0.w + qv.y * w1.w + qv.z * w2.w + qv.w * w3.w;
      }
      acc[j] = a;
    }
  }
  float4 bb = f4_load(&bias[e0]);
#pragma unroll
  for (int j = 0; j < 8; ++j) {
    acc[j].x += bb.x; acc[j].y += bb.y; acc[j].z += bb.z; acc[j].w += bb.w;
  }
  if (which == 0) {
#pragma unroll
    for (int j = 0; j < 8; ++j)
      f4_store(&qt_ws[((size_t)b * Nn + ng * 8 + j) * Ee + e0], acc[j]);
    return;
  }
  // ---- qs -> q_l, then qk2 / qb2 ----
  __syncthreads();
#pragma unroll
  for (int j = 0; j < 8; ++j)
    f4_store(&q_l[(ng * 8 + j) * 132 + e0], acc[j]);
  for (int h = 0; h < 4; ++h) {
    __syncthreads();
    for (int idx = t; idx < 1024; idx += 256) {  // stage Wk' rows (plain)
      int kk = idx >> 5, e4 = (idx & 31) << 2;
      f4_store(&W_l[kk * 128 + e4], f4_load(&Wkp[(h * 32 + kk) * Ee + e4]));
    }
    __syncthreads();
#pragma unroll
    for (int j = 0; j < 8; ++j) {
      const int n = ng * 8 + j;
      float4 a = make_float4(0.f, 0.f, 0.f, 0.f);
      for (int d0 = 0; d0 < 32; d0 += 4) {
        float4 qv = f4_load(&q_l[n * 132 + h * 32 + d0]);
        float4 w0 = f4_load(&W_l[(d0 + 0) * 128 + e0]);
        float4 w1 = f4_load(&W_l[(d0 + 1) * 128 + e0]);
        float4 w2 = f4_load(&W_l[(d0 + 2) * 128 + e0]);
        float4 w3 = f4_load(&W_l[(d0 + 3) * 128 + e0]);
        a.x += qv.x * w0.x + qv.y * w1.x + qv.z * w2.x + qv.w * w3.x;
        a.y += qv.x * w0.y + qv.y * w1.y + qv.z * w2.y + qv.w * w3.y;
        a.z += qv.x * w0.z + qv.y * w1.z + qv.z * w2.z + qv.w * w3.z;
        a.w += qv.x * w0.w + qv.y * w1.w + qv.z * w2.w + qv.w * w3.w;
      }
      f4_store(&qk2_ws[(((size_t)b * Nn + n) * Hh + h) * Ee + e0], a);
    }
  }
  __syncthreads();
  {  // qb2: thread -> (n, h)
    const int nn = t >> 2, h2 = t & 3;
    float s = 0.f;
    for (int d = 0; d < 32; ++d)
      s += q_l[nn * 132 + h2 * 32 + d] * bk_l[h2 * 32 + d];
    qb2_ws[((size_t)b * Nn + nn) * Hh + h2] = s;
  }
}

// ---------------- kt/vt projection: out layout [b][m][s][e] ----------------
// grid (64 b, 8 ngrp)
__global__ __launch_bounds__(256) void ktvt_kernel(
    const float* __restrict__ x,
    const float* __restrict__ tWk, const float* __restrict__ tbk,
    const float* __restrict__ tWv, const float* __restrict__ tbv,
    float* __restrict__ kt_ws, float* __restrict__ vt_ws) {
  __shared__ float x_l[32 * 132];   // [s][k]
  __shared__ float W_l[32 * 128];   // k-quarter transposed [k][e]
  const int b = blockIdx.x;
  const int n0 = blockIdx.y * 8;
  const int t = threadIdx.x;
  const int sg = t >> 5;            // 0..7 -> 4 s rows
  const int e4 = (t & 31) << 2;
  for (int ni = 0; ni < 8; ++ni) {
    const int n = n0 + ni;
    __syncthreads();  // prev compute done with x_l
    for (int idx = t; idx < 1024; idx += 256) {
      int s = idx >> 5, k4 = (idx & 31) << 2;
      f4_store(&x_l[s * 132 + k4],
               f4_load(&x[(((size_t)b * Ss + s) * Nn + n) * Ee + k4]));
    }
    for (int mat = 0; mat < 2; ++mat) {
      const float* Wg = mat ? tWv : tWk;
      const float* bg = mat ? tbv : tbk;
      float* og = mat ? vt_ws : kt_ws;
      float4 acc[4];
#pragma unroll
      for (int j = 0; j < 4; ++j) acc[j] = make_float4(0.f, 0.f, 0.f, 0.f);
      for (int kq = 0; kq < 4; ++kq) {
        __syncthreads();  // x ready / prev compute done with W_l
        for (int idx = t; idx < 1024; idx += 256) {
          int e = idx & 127, k0 = (idx >> 7) << 2;
          float4 w = f4_load(&Wg[e * Ee + kq * 32 + k0]);
          W_l[(k0 + 0) * 128 + e] = w.x;
          W_l[(k0 + 1) * 128 + e] = w.y;
          W_l[(k0 + 2) * 128 + e] = w.z;
          W_l[(k0 + 3) * 128 + e] = w.w;
        }
        __syncthreads();
        for (int k0 = 0; k0 < 32; k0 += 4) {
          float4 w0 = f4_load(&W_l[(k0 + 0) * 128 + e4]);
          float4 w1 = f4_load(&W_l[(k0 + 1) * 128 + e4]);
          float4 w2 = f4_load(&W_l[(k0 + 2) * 128 + e4]);
          float4 w3 = f4_load(&W_l[(k0 + 3) * 128 + e4]);
#pragma unroll
          for (int j = 0; j < 4; ++j) {
            float4 xv = f4_load(&x_l[(sg * 4 + j) * 132 + kq * 32 + k0]);
            acc[j].x += xv.x * w0.x + xv.y * w1.x + xv.z * w2.x + xv.w * w3.x;
            acc[j].y += xv.x * w0.y + xv.y * w1.y + xv.z * w2.y + xv.w * w3.y;
            acc[j].z += xv.x * w0.z + xv.y * w1.z + xv.z * w2.z + xv.w * w3.z;
            acc[j].w += xv.x * w0.w + xv.y * w1.w + xv.z * w2.w + xv.w * w3.w;
          }
        }
      }
      float4 bb = f4_load(&bg[e4]);
#pragma unroll
      for (int j = 0; j < 4; ++j) {
        float4 o;
        o.x = acc[j].x + bb.x; o.y = acc[j].y + bb.y;
        o.z = acc[j].z + bb.z; o.w = acc[j].w + bb.w;
        f4_store(&og[(((size_t)b * Nn + n) * Ss + sg * 4 + j) * Ee + e4], o);
      }
    }
  }
}

// ---------------- main fused kernel ----------------------------------------
// grid dim3(128, 8): bx = b*2+ms, by = n-chunk; same-b blocks differ in
// linear id by multiples of 128 (mod 8 == 0 -> same XCD under round-robin).
// Block: 256 thr; thread -> (n = t>>5, lane = t&31).
__global__ __launch_bounds__(256, 4) void main_kernel(
    const float* __restrict__ kt_ws, const float* __restrict__ vt_ws,
    const float* __restrict__ qt_ws, const float* __restrict__ qk2_ws,
    const float* __restrict__ qb2_ws, const int* __restrict__ adj,
    float* __restrict__ pctxw, float* __restrict__ pM,
    float* __restrict__ pL) {
  __shared__ float kv[32 * 132];       // kt then vt tile, stride 132
  __shared__ float p_l[8 * 4 * 36];    // probs, stride 36 (16B-aligned rows)
  __shared__ float qt_l[8 * 128];
  __shared__ int adj_l[8 * 64];
  const int bx = blockIdx.x;
  const int b = bx >> 1, ms = bx & 1;
  const int n0 = blockIdx.y * 8;
  const int m0 = ms * 32;
  const int t = threadIdx.x;
  const int n = t >> 5;
  const int lane = t & 31;
  const int e4 = lane << 2;
  const int hh = lane >> 3;  // h owned in the PV phase

  for (int idx = t; idx < 1024; idx += 256)
    qt_l[idx] = qt_ws[((size_t)b * Nn + n0 + (idx >> 7)) * Ee + (idx & 127)];
  for (int idx = t; idx < 512; idx += 256)
    adj_l[idx] = adj[(n0 + (idx >> 6)) * Nn + (idx & 63)];

  // m-invariant per-thread state
  float4 qk2r[4];
  float qb2r[4];
#pragma unroll
  for (int h = 0; h < 4; ++h) {
    qk2r[h] = f4_load(&qk2_ws[(((size_t)b * Nn + n0 + n) * Hh + h) * Ee + e4]);
    qb2r[h] = qb2_ws[((size_t)b * Nn + n0 + n) * Hh + h];
  }
  float4 cw[4];
  float Mh[4], Lh[4];
#pragma unroll
  for (int h = 0; h < 4; ++h) {
    cw[h] = make_float4(0.f, 0.f, 0.f, 0.f);
    Mh[h] = -1e30f;
    Lh[h] = 0.f;
  }
  __syncthreads();

  for (int mi = 0; mi < 32; ++mi) {
    const int m = m0 + mi;
    const size_t kvbase = ((size_t)b * Nn + m) * Ss * Ee;
    // ---- stage kt ----
    for (int p = 0; p < 4; ++p) {
      int idx = p * 256 + t;
      int s = idx >> 5, e = (idx & 31) << 2;
      f4_store(&kv[s * 132 + e], f4_load(&kt_ws[kvbase + s * Ee + e]));
    }
    __syncthreads();
    // ---- scores (thread = (n, s=lane)) + wave-parallel softmax ----
    float pr[4];
#pragma unroll
    for (int h = 0; h < 4; ++h) {
      float a = 0.f;
#pragma unroll
      for (int d0 = 0; d0 < 32; d0 += 4) {
        float4 qa = f4_load(&qt_l[n * 128 + h * 32 + d0]);
        float4 ka = f4_load(&kv[lane * 132 + h * 32 + d0]);
        a += dot4(qa, ka);
      }
      pr[h] = a * SCALE;
    }
#pragma unroll
    for (int h = 0; h < 4; ++h) {
      float mx = pr[h];
#pragma unroll
      for (int msk = 1; msk < 32; msk <<= 1)
        mx = fmaxf(mx, __shfl_xor(mx, msk));
      float w = __expf(pr[h] - mx);
      float sum = w;
#pragma unroll
      for (int msk = 1; msk < 32; msk <<= 1) sum += __shfl_xor(sum, msk);
      p_l[(n * 4 + h) * 36 + lane] = w * (1.0f / sum);
    }
    __syncthreads();  // p ready; kt reads done
    // ---- stage vt ----
    for (int p = 0; p < 4; ++p) {
      int idx = p * 256 + t;
      int s = idx >> 5, e = (idx & 31) << 2;
      f4_store(&kv[s * 132 + e], f4_load(&vt_ws[kvbase + s * Ee + e]));
    }
    __syncthreads();
    // ---- PV (thread = (n, e4)) ----
    float4 c1 = make_float4(0.f, 0.f, 0.f, 0.f);
    const float* prow = &p_l[(n * 4 + hh) * 36];
#pragma unroll
    for (int s4 = 0; s4 < 8; ++s4) {
      float4 pw = f4_load(&prow[s4 * 4]);
      float4 v0 = f4_load(&kv[(s4 * 4 + 0) * 132 + e4]);
      float4 v1 = f4_load(&kv[(s4 * 4 + 1) * 132 + e4]);
      float4 v2 = f4_load(&kv[(s4 * 4 + 2) * 132 + e4]);
      float4 v3 = f4_load(&kv[(s4 * 4 + 3) * 132 + e4]);
      c1.x += pw.x * v0.x + pw.y * v1.x + pw.z * v2.x + pw.w * v3.x;
      c1.y += pw.x * v0.y + pw.y * v1.y + pw.z * v2.y + pw.w * v3.y;
      c1.z += pw.x * v0.z + pw.y * v1.z + pw.z * v2.z + pw.w * v3.z;
      c1.w += pw.x * v0.w + pw.y * v1.w + pw.z * v2.w + pw.w * v3.w;
    }
    // ---- sc2: FULL e-contraction per head (the round-3 bug was summing
    //      only each head's diagonal 32-wide e-block). Each lane holds the
    //      e4..e4+3 slice of ctx1; butterfly over all 32 lanes per head. ----
    const int am = adj_l[n * 64 + m];
    float s2[4];
#pragma unroll
    for (int h2 = 0; h2 < 4; ++h2) {
      float part = dot4(qk2r[h2], c1);
#pragma unroll
      for (int msk = 1; msk < 32; msk <<= 1) part += __shfl_xor(part, msk);
      s2[h2] = am ? (part + qb2r[h2]) * SCALE : -1e30f;
    }
    // ---- online update (replicated across lanes; consistent) ----
#pragma unroll
    for (int h2 = 0; h2 < 4; ++h2) {
      float mnew = fmaxf(Mh[h2], s2[h2]);
      float r = __expf(Mh[h2] - mnew);
      float w = (s2[h2] < -1e29f) ? 0.f : __expf(s2[h2] - mnew);
      Lh[h2] = Lh[h2] * r + w;
      cw[h2].x = cw[h2].x * r + w * c1.x;
      cw[h2].y = cw[h2].y * r + w * c1.y;
      cw[h2].z = cw[h2].z * r + w * c1.z;
      cw[h2].w = cw[h2].w * r + w * c1.w;
      Mh[h2] = mnew;
    }
    __syncthreads();  // PV done reading kv/p before next stage
  }
  // ---- write partials ----
  const size_t pidx = ((size_t)(ms * Bb + b) * Nn + n0 + n);
#pragma unroll
  for (int h2 = 0; h2 < 4; ++h2)
    f4_store(&pctxw[(pidx * 4 + h2) * Ee + e4], cw[h2]);
  if (lane == 0) {
#pragma unroll
    for (int h2 = 0; h2 < 4; ++h2) {
      pM[pidx * 4 + h2] = Mh[h2];
      pL[pidx * 4 + h2] = Lh[h2];
    }
  }
}

// ---------------- reducer: combine partials, apply Wv', sWo ----------------
// grid (64 b, 8 nc)
__global__ __launch_bounds__(256) void reduce_kernel(
    const float* __restrict__ pctxw, const float* __restrict__ pM,
    const float* __restrict__ pL, const float* __restrict__ Wvp,
    const float* __restrict__ bvp, const float* __restrict__ sWo,
    const float* __restrict__ sbo, float* __restrict__ out) {
  __shared__ float cwf[8 * 4 * 132];
  __shared__ float c2l[8 * 132];
  const int b = blockIdx.x;
  const int n0 = blockIdx.y * 8;
  const int t = threadIdx.x;
  const int n = t >> 5;
  const int lane = t & 31;
  const int e4 = lane << 2;
  const int gn = n0 + n;
#pragma unroll
  for (int h = 0; h < 4; ++h) {
    const size_t i0 = ((size_t)(0 * Bb + b) * Nn + gn) * 4 + h;
    const size_t i1 = ((size_t)(1 * Bb + b) * Nn + gn) * 4 + h;
    float M0 = pM[i0], M1 = pM[i1];
    float L0 = pL[i0], L1 = pL[i1];
    float Msx = fmaxf(M0, M1);
    float r0 = __expf(M0 - Msx), r1 = __expf(M1 - Msx);
    float inv = 1.0f / (r0 * L0 + r1 * L1);
    float4 c0 = f4_load(&pctxw[i0 * Ee + e4]);
    float4 c1 = f4_load(&pctxw[i1 * Ee + e4]);
    float4 res;
    res.x = (r0 * c0.x + r1 * c1.x) * inv;
    res.y = (r0 * c0.y + r1 * c1.y) * inv;
    res.z = (r0 * c0.z + r1 * c1.z) * inv;
    res.w = (r0 * c0.w + r1 * c1.w) * inv;
    f4_store(&cwf[(n * 4 + h) * 132 + e4], res);
  }
  __syncthreads();
  // ctx2[n][k4..k4+3] = bv'[k] + sum_e Wv'[k][e]*cwf[n][h(k)][e]
  {
    const int k4 = lane << 2;
    const int h = lane >> 3;
    float4 a = f4_load(&bvp[k4]);
    for (int ee = 0; ee < 128; ee += 4) {
      float4 cv = f4_load(&cwf[(n * 4 + h) * 132 + ee]);
      float4 w0 = f4_load(&Wvp[(k4 + 0) * Ee + ee]);
      float4 w1 = f4_load(&Wvp[(k4 + 1) * Ee + ee]);
      float4 w2 = f4_load(&Wvp[(k4 + 2) * Ee + ee]);
      float4 w3 = f4_load(&Wvp[(k4 + 3) * Ee + ee]);
      a.x += dot4(w0, cv);
      a.y += dot4(w1, cv);
      a.z += dot4(w2, cv);
      a.w += dot4(w3, cv);
    }
    f4_store(&c2l[n * 132 + k4], a);
  }
  __syncthreads();
  // out[b][gn][e4..] = sbo + sWo @ ctx2
  {
    float4 o = f4_load(&sbo[e4]);
    for (int k0 = 0; k0 < 128; k0 += 4) {
      float4 cv = f4_load(&c2l[n * 132 + k0]);
      float4 w0 = f4_load(&sWo[(e4 + 0) * Ee + k0]);
      float4 w1 = f4_load(&sWo[(e4 + 1) * Ee + k0]);
      float4 w2 = f4_load(&sWo[(e4 + 2) * Ee + k0]);
      float4 w3 = f4_load(&sWo[(e4 + 3) * Ee + k0]);
      o.x += dot4(w0, cv);
      o.y += dot4(w1, cv);
      o.z += dot4(w2, cv);
      o.w += dot4(w3, cv);
    }
    f4_store(&out[((size_t)b * Nn + gn) * Ee + e4], o);
  }
}

// ---------------------------------------------------------------------------
extern "C" void kernel_launch(void* const* d_in, const int* in_sizes, int n_in,
                              void* d_out, int out_size, void* d_ws,
                              size_t ws_size, hipStream_t stream) {
  const float* x = (const float*)d_in[0];
  const int* adj = (const int*)d_in[1];
  const float* tWq = (const float*)d_in[2];
  const float* tbq = (const float*)d_in[3];
  const float* tWk = (const float*)d_in[4];
  const float* tbk = (const float*)d_in[5];
  const float* tWv = (const float*)d_in[6];
  const float* tbv = (const float*)d_in[7];
  const float* tWo = (const float*)d_in[8];
  const float* tbo = (const float*)d_in[9];
  const float* sWq = (const float*)d_in[10];
  const float* sbq = (const float*)d_in[11];
  const float* sWk = (const float*)d_in[12];
  const float* sbk = (const float*)d_in[13];
  const float* sWv = (const float*)d_in[14];
  const float* sbv = (const float*)d_in[15];
  const float* sWo = (const float*)d_in[16];
  const float* sbo = (const float*)d_in[17];
  float* out = (float*)d_out;

  float* ws = (float*)d_ws;
  const size_t ktvt_elems = (size_t)Bb * Nn * Ss * Ee;  // 16,777,216
  float* kt_ws = ws;
  float* vt_ws = kt_ws + ktvt_elems;
  float* qt_ws = vt_ws + ktvt_elems;                       // 524,288
  float* qk2_ws = qt_ws + (size_t)Bb * Nn * Ee;            // 2,097,152
  float* qb2_ws = qk2_ws + (size_t)Bb * Nn * Hh * Ee;      // 16,384
  float* Wkp = qb2_ws + (size_t)Bb * Nn * Hh;
  float* Wvp = Wkp + Ee * Ee;
  float* bkp = Wvp + Ee * Ee;
  float* bvp = bkp + Ee;
  float* pctxw = bvp + Ee;                                 // MS*B*N*4*128
  float* pM = pctxw + (size_t)MS * Bb * Nn * 4 * Ee;       // MS*B*N*4
  float* pL = pM + (size_t)MS * Bb * Nn * 4;

  fuse_weights_kernel<<<dim3(Ee, 2), 128, 0, stream>>>(
      sWk, sbk, sWv, sbv, tWo, tbo, Wkp, bkp, Wvp, bvp);
  qproj_kernel<<<dim3(Bb, 2), 256, 0, stream>>>(
      x, tWq, tbq, sWq, sbq, Wkp, bkp, qt_ws, qk2_ws, qb2_ws);
  ktvt_kernel<<<dim3(Bb, 8), 256, 0, stream>>>(x, tWk, tbk, tWv, tbv, kt_ws,
                                               vt_ws);
  main_kernel<<<dim3(Bb * MS, 8), 256, 0, stream>>>(
      kt_ws, vt_ws, qt_ws, qk2_ws, qb2_ws, adj, pctxw, pM, pL);
  reduce_kernel<<<dim3(Bb, 8), 256, 0, stream>>>(pctxw, pM, pL, Wvp, bvp, sWo,
                                                 sbo, out);
}

// Round 6
// 589.412 us; speedup vs baseline: 2.9870x; 1.2934x over previous
//
#include <hip/hip_runtime.h>

// ---------------------------------------------------------------------------
// Double attention, round 6 = round-5 source resubmitted verbatim (round 5
// bench was a GPUAcquisitionTimeout; no signal). f32.
//   B=64 S=32 N=64 E=128 H=4 D=32
// vs round 4 (762 us total; ktvt 335 us VALUBusy 27%, main ~330 us):
//  * ktvt rewritten: block = (b,s) tile -> x[64 n][128 e] contiguous, staged
//    once; W quarters staged 4x/block (was 64x); 64 acc/thread.
//  * main: 16-n chunks, 512 threads; merged kt+vt staging (3 barriers/m);
//    grid (b, chunk) so same-b blocks share XCD -> kt/vt L2-resident.
// ---------------------------------------------------------------------------

constexpr int Bb = 64, Ss = 32, Nn = 64, Ee = 128, Hh = 4, Dd = 32;
constexpr int MS = 2;                       // m-split factor
constexpr float SCALE = 0.17677669529663687f;  // 1/sqrt(32)

__device__ __forceinline__ float4 f4_load(const float* p) {
  return *reinterpret_cast<const float4*>(p);
}
__device__ __forceinline__ void f4_store(float* p, float4 v) {
  *reinterpret_cast<float4*>(p) = v;
}
__device__ __forceinline__ float dot4(float4 a, float4 b) {
  return a.x * b.x + a.y * b.y + a.z * b.z + a.w * b.w;
}

// ---------------- fold stage-2 K/V weights through t_Wo --------------------
__global__ __launch_bounds__(128) void fuse_weights_kernel(
    const float* __restrict__ sWk, const float* __restrict__ sbk,
    const float* __restrict__ sWv, const float* __restrict__ sbv,
    const float* __restrict__ tWo, const float* __restrict__ tbo,
    float* __restrict__ Wkp, float* __restrict__ bkp,
    float* __restrict__ Wvp, float* __restrict__ bvp) {
  const int i = blockIdx.x;
  const int which = blockIdx.y;
  const float* sW = which ? sWv : sWk;
  const float* sb = which ? sbv : sbk;
  float* Wp = which ? Wvp : Wkp;
  float* bp = which ? bvp : bkp;
  __shared__ float srow[Ee];
  const int t = threadIdx.x;
  srow[t] = sW[i * Ee + t];
  __syncthreads();
  float acc = 0.f;
  for (int k = 0; k < Ee; ++k) acc += srow[k] * tWo[k * Ee + t];
  Wp[i * Ee + t] = acc;
  if (t == 0) {
    float bb = sb[i];
    for (int k = 0; k < Ee; ++k) bb += srow[k] * tbo[k];
    bp[i] = bb;
  }
}

// ---------------- q projections + qk2/qb2 ----------------------------------
// grid (B, 2). which=0: qt = q@tWq^T+tbq -> qt_ws.
// which=1: qs = q@sWq^T+sbq (kept in LDS), then
//   qk2[n,h,e] = sum_d qs[n,hD+d]*Wk'[hD+d][e], qb2[n,h] = sum_d qs*bk'.
__global__ __launch_bounds__(256) void qproj_kernel(
    const float* __restrict__ x,
    const float* __restrict__ tWq, const float* __restrict__ tbq,
    const float* __restrict__ sWq, const float* __restrict__ sbq,
    const float* __restrict__ Wkp, const float* __restrict__ bkp,
    float* __restrict__ qt_ws, float* __restrict__ qk2_ws,
    float* __restrict__ qb2_ws) {
  __shared__ float q_l[64 * 132];   // [n][132]
  __shared__ float W_l[32 * 128];   // k-quarter, [k][e]
  __shared__ float bk_l[128];
  const int b = blockIdx.x;
  const int which = blockIdx.y;
  const float* W = which ? sWq : tWq;
  const float* bias = which ? sbq : tbq;
  const int t = threadIdx.x;
  // stage q rows (x[b, S-1, n, :])
  for (int idx = t; idx < 2048; idx += 256) {
    int nn = idx >> 5, e4 = (idx & 31) << 2;
    f4_store(&q_l[nn * 132 + e4],
             f4_load(&x[(((size_t)b * Ss + (Ss - 1)) * Nn + nn) * Ee + e4]));
  }
  if (which && t < 32) f4_store(&bk_l[t * 4], f4_load(&bkp[t * 4]));

  const int ng = t >> 5;
  const int e0 = (t & 31) << 2;
  float4 acc[8];
#pragma unroll
  for (int j = 0; j < 8; ++j) acc[j] = make_float4(0.f, 0.f, 0.f, 0.f);

  for (int kq = 0; kq < 4; ++kq) {
    __syncthreads();
    // stage W quarter transposed: W_l[k][e] from W[e][kq*32+k]
    for (int idx = t; idx < 1024; idx += 256) {
      int e = idx & 127, k0 = (idx >> 7) << 2;
      float4 w = f4_load(&W[e * Ee + kq * 32 + k0]);
      W_l[(k0 + 0) * 128 + e] = w.x;
      W_l[(k0 + 1) * 128 + e] = w.y;
      W_l[(k0 + 2) * 128 + e] = w.z;
      W_l[(k0 + 3) * 128 + e] = w.w;
    }
    __syncthreads();
#pragma unroll
    for (int j = 0; j < 8; ++j) {
      const int n = ng * 8 + j;
      float4 a = acc[j];
      for (int k0 = 0; k0 < 32; k0 += 4) {
        float4 qv = f4_load(&q_l[n * 132 + kq * 32 + k0]);
        float4 w0 = f4_load(&W_l[(k0 + 0) * 128 + e0]);
        float4 w1 = f4_load(&W_l[(k0 + 1) * 128 + e0]);
        float4 w2 = f4_load(&W_l[(k0 + 2) * 128 + e0]);
        float4 w3 = f4_load(&W_l[(k0 + 3) * 128 + e0]);
        a.x += qv.x * w0.x + qv.y * w1.x + qv.z * w2.x + qv.w * w3.x;
        a.y += qv.x * w0.y + qv.y * w1.y + qv.z * w2.y + qv.w * w3.y;
        a.z += qv.x * w0.z + qv.y * w1.z + qv.z * w2.z + qv.w * w3.z;
        a.w += qv.x * w0.w + qv.y * w1.w + qv.z * w2.w + qv.w * w3.w;
      }
      acc[j] = a;
    }
  }
  float4 bb = f4_load(&bias[e0]);
#pragma unroll
  for (int j = 0; j < 8; ++j) {
    acc[j].x += bb.x; acc[j].y += bb.y; acc[j].z += bb.z; acc[j].w += bb.w;
  }
  if (which == 0) {
#pragma unroll
    for (int j = 0; j < 8; ++j)
      f4_store(&qt_ws[((size_t)b * Nn + ng * 8 + j) * Ee + e0], acc[j]);
    return;
  }
  // ---- qs -> q_l, then qk2 / qb2 ----
  __syncthreads();
#pragma unroll
  for (int j = 0; j < 8; ++j)
    f4_store(&q_l[(ng * 8 + j) * 132 + e0], acc[j]);
  for (int h = 0; h < 4; ++h) {
    __syncthreads();
    for (int idx = t; idx < 1024; idx += 256) {  // stage Wk' rows (plain)
      int kk = idx >> 5, e4 = (idx & 31) << 2;
      f4_store(&W_l[kk * 128 + e4], f4_load(&Wkp[(h * 32 + kk) * Ee + e4]));
    }
    __syncthreads();
#pragma unroll
    for (int j = 0; j < 8; ++j) {
      const int n = ng * 8 + j;
      float4 a = make_float4(0.f, 0.f, 0.f, 0.f);
      for (int d0 = 0; d0 < 32; d0 += 4) {
        float4 qv = f4_load(&q_l[n * 132 + h * 32 + d0]);
        float4 w0 = f4_load(&W_l[(d0 + 0) * 128 + e0]);
        float4 w1 = f4_load(&W_l[(d0 + 1) * 128 + e0]);
        float4 w2 = f4_load(&W_l[(d0 + 2) * 128 + e0]);
        float4 w3 = f4_load(&W_l[(d0 + 3) * 128 + e0]);
        a.x += qv.x * w0.x + qv.y * w1.x + qv.z * w2.x + qv.w * w3.x;
        a.y += qv.x * w0.y + qv.y * w1.y + qv.z * w2.y + qv.w * w3.y;
        a.z += qv.x * w0.z + qv.y * w1.z + qv.z * w2.z + qv.w * w3.z;
        a.w += qv.x * w0.w + qv.y * w1.w + qv.z * w2.w + qv.w * w3.w;
      }
      f4_store(&qk2_ws[(((size_t)b * Nn + n) * Hh + h) * Ee + e0], a);
    }
  }
  __syncthreads();
  {  // qb2: thread -> (n, h)
    const int nn = t >> 2, h2 = t & 3;
    float s = 0.f;
    for (int d = 0; d < 32; ++d)
      s += q_l[nn * 132 + h2 * 32 + d] * bk_l[h2 * 32 + d];
    qb2_ws[((size_t)b * Nn + nn) * Hh + h2] = s;
  }
}

// ---------------- kt/vt projection: block = (b, s) -------------------------
// x[b][s][:][:] is 64x128 contiguous -> staged once. W quarters staged
// 4x/block (both mats). Thread (ng=t>>4, tx=t&15): 4 n-rows x (2+2) f4 cols.
__global__ __launch_bounds__(256, 2) void ktvt_kernel(
    const float* __restrict__ x,
    const float* __restrict__ tWk, const float* __restrict__ tbk,
    const float* __restrict__ tWv, const float* __restrict__ tbv,
    float* __restrict__ kt_ws, float* __restrict__ vt_ws) {
  __shared__ float x_l[64 * 132];    // [n][132]
  __shared__ float Wk_l[32 * 132];   // quarter transposed [k][e]
  __shared__ float Wv_l[32 * 132];
  const int b = blockIdx.x;
  const int s = blockIdx.y;
  const int t = threadIdx.x;
  const int ng = t >> 4;        // 0..15 -> 4 n rows each
  const int tx = t & 15;        // cols tx*4 and 64+tx*4
  const size_t xbase = (((size_t)b * Ss + s) * Nn) * Ee;
  for (int idx = t; idx < 2048; idx += 256) {
    int nn = idx >> 5, e4 = (idx & 31) << 2;
    f4_store(&x_l[nn * 132 + e4], f4_load(&x[xbase + nn * Ee + e4]));
  }
  float4 aK[4][2], aV[4][2];
#pragma unroll
  for (int j = 0; j < 4; ++j)
#pragma unroll
    for (int c = 0; c < 2; ++c) {
      aK[j][c] = make_float4(0.f, 0.f, 0.f, 0.f);
      aV[j][c] = make_float4(0.f, 0.f, 0.f, 0.f);
    }
  for (int kq = 0; kq < 4; ++kq) {
    __syncthreads();  // x ready (kq=0) / prev compute done with W tiles
    for (int idx = t; idx < 2048; idx += 256) {
      int which = idx >> 10, i2 = idx & 1023;
      int e = i2 & 127, k0 = (i2 >> 7) << 2;
      const float* Wg = which ? tWv : tWk;
      float* Wl = which ? Wv_l : Wk_l;
      float4 w = f4_load(&Wg[e * Ee + kq * 32 + k0]);
      Wl[(k0 + 0) * 132 + e] = w.x;
      Wl[(k0 + 1) * 132 + e] = w.y;
      Wl[(k0 + 2) * 132 + e] = w.z;
      Wl[(k0 + 3) * 132 + e] = w.w;
    }
    __syncthreads();
#pragma unroll 8
    for (int k = 0; k < 32; ++k) {
      float xv[4];
#pragma unroll
      for (int j = 0; j < 4; ++j)
        xv[j] = x_l[(ng * 4 + j) * 132 + kq * 32 + k];
      float4 wk0 = f4_load(&Wk_l[k * 132 + tx * 4]);
      float4 wk1 = f4_load(&Wk_l[k * 132 + 64 + tx * 4]);
      float4 wv0 = f4_load(&Wv_l[k * 132 + tx * 4]);
      float4 wv1 = f4_load(&Wv_l[k * 132 + 64 + tx * 4]);
#pragma unroll
      for (int j = 0; j < 4; ++j) {
        float a = xv[j];
        aK[j][0].x += a * wk0.x; aK[j][0].y += a * wk0.y;
        aK[j][0].z += a * wk0.z; aK[j][0].w += a * wk0.w;
        aK[j][1].x += a * wk1.x; aK[j][1].y += a * wk1.y;
        aK[j][1].z += a * wk1.z; aK[j][1].w += a * wk1.w;
        aV[j][0].x += a * wv0.x; aV[j][0].y += a * wv0.y;
        aV[j][0].z += a * wv0.z; aV[j][0].w += a * wv0.w;
        aV[j][1].x += a * wv1.x; aV[j][1].y += a * wv1.y;
        aV[j][1].z += a * wv1.z; aV[j][1].w += a * wv1.w;
      }
    }
  }
  float4 bk0 = f4_load(&tbk[tx * 4]);
  float4 bk1 = f4_load(&tbk[64 + tx * 4]);
  float4 bv0 = f4_load(&tbv[tx * 4]);
  float4 bv1 = f4_load(&tbv[64 + tx * 4]);
#pragma unroll
  for (int j = 0; j < 4; ++j) {
    const int n = ng * 4 + j;
    const size_t obase = (((size_t)b * Nn + n) * Ss + s) * Ee;
    float4 o;
    o.x = aK[j][0].x + bk0.x; o.y = aK[j][0].y + bk0.y;
    o.z = aK[j][0].z + bk0.z; o.w = aK[j][0].w + bk0.w;
    f4_store(&kt_ws[obase + tx * 4], o);
    o.x = aK[j][1].x + bk1.x; o.y = aK[j][1].y + bk1.y;
    o.z = aK[j][1].z + bk1.z; o.w = aK[j][1].w + bk1.w;
    f4_store(&kt_ws[obase + 64 + tx * 4], o);
    o.x = aV[j][0].x + bv0.x; o.y = aV[j][0].y + bv0.y;
    o.z = aV[j][0].z + bv0.z; o.w = aV[j][0].w + bv0.w;
    f4_store(&vt_ws[obase + tx * 4], o);
    o.x = aV[j][1].x + bv1.x; o.y = aV[j][1].y + bv1.y;
    o.z = aV[j][1].z + bv1.z; o.w = aV[j][1].w + bv1.w;
    f4_store(&vt_ws[obase + 64 + tx * 4], o);
  }
}

// ---------------- main fused kernel ----------------------------------------
// grid dim3(64, 8): bx = b, by = chunk (ms = by>>2, nc = by&3).
// Linear block id = by*64+bx -> id%8 = b%8: all 8 blocks of one b share an
// XCD -> kt/vt[b] (4 MB) stays L2-resident. 512 thr: (n = t>>5 in 0..15,
// lane = t&31). All 512 blocks co-resident at 2 blocks/CU.
__global__ __launch_bounds__(512, 4) void main_kernel(
    const float* __restrict__ kt_ws, const float* __restrict__ vt_ws,
    const float* __restrict__ qt_ws, const float* __restrict__ qk2_ws,
    const float* __restrict__ qb2_ws, const int* __restrict__ adj,
    float* __restrict__ pctxw, float* __restrict__ pM,
    float* __restrict__ pL) {
  __shared__ float kvK[32 * 132];      // kt tile, stride 132
  __shared__ float kvV[32 * 132];      // vt tile
  __shared__ float p_l[16 * 4 * 36];   // probs
  __shared__ float qt_l[16 * 128];
  __shared__ int adj_l[16 * 64];
  const int b = blockIdx.x;
  const int chunk = blockIdx.y;
  const int ms = chunk >> 2;
  const int n0 = (chunk & 3) * 16;
  const int m0 = ms * 32;
  const int t = threadIdx.x;
  const int n = t >> 5;
  const int lane = t & 31;
  const int e4 = lane << 2;
  const int hh = lane >> 3;  // h owned in the PV phase

  for (int idx = t; idx < 2048; idx += 512)
    qt_l[idx] = qt_ws[((size_t)b * Nn + n0 + (idx >> 7)) * Ee + (idx & 127)];
  for (int idx = t; idx < 1024; idx += 512)
    adj_l[idx] = adj[(n0 + (idx >> 6)) * Nn + (idx & 63)];

  // m-invariant per-thread state
  float4 qk2r[4];
  float qb2r[4];
#pragma unroll
  for (int h = 0; h < 4; ++h) {
    qk2r[h] = f4_load(&qk2_ws[(((size_t)b * Nn + n0 + n) * Hh + h) * Ee + e4]);
    qb2r[h] = qb2_ws[((size_t)b * Nn + n0 + n) * Hh + h];
  }
  float4 cw[4];
  float Mh[4], Lh[4];
#pragma unroll
  for (int h = 0; h < 4; ++h) {
    cw[h] = make_float4(0.f, 0.f, 0.f, 0.f);
    Mh[h] = -1e30f;
    Lh[h] = 0.f;
  }
  __syncthreads();

  for (int mi = 0; mi < 32; ++mi) {
    const int m = m0 + mi;
    const size_t kvbase = ((size_t)b * Nn + m) * Ss * Ee;
    // ---- stage kt AND vt (merged; 3 barriers per m total) ----
#pragma unroll
    for (int p = 0; p < 2; ++p) {
      int idx = p * 512 + t;
      int s = idx >> 5, e = (idx & 31) << 2;
      f4_store(&kvK[s * 132 + e], f4_load(&kt_ws[kvbase + s * Ee + e]));
    }
#pragma unroll
    for (int p = 0; p < 2; ++p) {
      int idx = p * 512 + t;
      int s = idx >> 5, e = (idx & 31) << 2;
      f4_store(&kvV[s * 132 + e], f4_load(&vt_ws[kvbase + s * Ee + e]));
    }
    __syncthreads();
    // ---- scores (thread = (n, s=lane)) + wave-parallel softmax ----
    float pr[4];
#pragma unroll
    for (int h = 0; h < 4; ++h) {
      float a = 0.f;
#pragma unroll
      for (int d0 = 0; d0 < 32; d0 += 4) {
        float4 qa = f4_load(&qt_l[n * 128 + h * 32 + d0]);
        float4 ka = f4_load(&kvK[lane * 132 + h * 32 + d0]);
        a += dot4(qa, ka);
      }
      pr[h] = a * SCALE;
    }
#pragma unroll
    for (int h = 0; h < 4; ++h) {
      float mx = pr[h];
#pragma unroll
      for (int msk = 1; msk < 32; msk <<= 1)
        mx = fmaxf(mx, __shfl_xor(mx, msk));
      float w = __expf(pr[h] - mx);
      float sum = w;
#pragma unroll
      for (int msk = 1; msk < 32; msk <<= 1) sum += __shfl_xor(sum, msk);
      p_l[(n * 4 + h) * 36 + lane] = w * (1.0f / sum);
    }
    __syncthreads();  // p ready
    // ---- PV (thread = (n, e4)) ----
    float4 c1 = make_float4(0.f, 0.f, 0.f, 0.f);
    const float* prow = &p_l[(n * 4 + hh) * 36];
#pragma unroll
    for (int s4 = 0; s4 < 8; ++s4) {
      float4 pw = f4_load(&prow[s4 * 4]);
      float4 v0 = f4_load(&kvV[(s4 * 4 + 0) * 132 + e4]);
      float4 v1 = f4_load(&kvV[(s4 * 4 + 1) * 132 + e4]);
      float4 v2 = f4_load(&kvV[(s4 * 4 + 2) * 132 + e4]);
      float4 v3 = f4_load(&kvV[(s4 * 4 + 3) * 132 + e4]);
      c1.x += pw.x * v0.x + pw.y * v1.x + pw.z * v2.x + pw.w * v3.x;
      c1.y += pw.x * v0.y + pw.y * v1.y + pw.z * v2.y + pw.w * v3.y;
      c1.z += pw.x * v0.z + pw.y * v1.z + pw.z * v2.z + pw.w * v3.z;
      c1.w += pw.x * v0.w + pw.y * v1.w + pw.z * v2.w + pw.w * v3.w;
    }
    // ---- sc2: full e-contraction per head (32-lane butterfly) ----
    const int am = adj_l[n * 64 + m];
    float s2[4];
#pragma unroll
    for (int h2 = 0; h2 < 4; ++h2) {
      float part = dot4(qk2r[h2], c1);
#pragma unroll
      for (int msk = 1; msk < 32; msk <<= 1) part += __shfl_xor(part, msk);
      s2[h2] = am ? (part + qb2r[h2]) * SCALE : -1e30f;
    }
    // ---- online update (replicated across lanes; consistent) ----
#pragma unroll
    for (int h2 = 0; h2 < 4; ++h2) {
      float mnew = fmaxf(Mh[h2], s2[h2]);
      float r = __expf(Mh[h2] - mnew);
      float w = (s2[h2] < -1e29f) ? 0.f : __expf(s2[h2] - mnew);
      Lh[h2] = Lh[h2] * r + w;
      cw[h2].x = cw[h2].x * r + w * c1.x;
      cw[h2].y = cw[h2].y * r + w * c1.y;
      cw[h2].z = cw[h2].z * r + w * c1.z;
      cw[h2].w = cw[h2].w * r + w * c1.w;
      Mh[h2] = mnew;
    }
    __syncthreads();  // done reading kv/p before next stage
  }
  // ---- write partials ----
  const size_t pidx = ((size_t)(ms * Bb + b) * Nn + n0 + n);
#pragma unroll
  for (int h2 = 0; h2 < 4; ++h2)
    f4_store(&pctxw[(pidx * 4 + h2) * Ee + e4], cw[h2]);
  if (lane == 0) {
#pragma unroll
    for (int h2 = 0; h2 < 4; ++h2) {
      pM[pidx * 4 + h2] = Mh[h2];
      pL[pidx * 4 + h2] = Lh[h2];
    }
  }
}

// ---------------- reducer: combine partials, apply Wv', sWo ----------------
// grid (64 b, 8 nc)
__global__ __launch_bounds__(256) void reduce_kernel(
    const float* __restrict__ pctxw, const float* __restrict__ pM,
    const float* __restrict__ pL, const float* __restrict__ Wvp,
    const float* __restrict__ bvp, const float* __restrict__ sWo,
    const float* __restrict__ sbo, float* __restrict__ out) {
  __shared__ float cwf[8 * 4 * 132];
  __shared__ float c2l[8 * 132];
  const int b = blockIdx.x;
  const int n0 = blockIdx.y * 8;
  const int t = threadIdx.x;
  const int n = t >> 5;
  const int lane = t & 31;
  const int e4 = lane << 2;
  const int gn = n0 + n;
#pragma unroll
  for (int h = 0; h < 4; ++h) {
    const size_t i0 = ((size_t)(0 * Bb + b) * Nn + gn) * 4 + h;
    const size_t i1 = ((size_t)(1 * Bb + b) * Nn + gn) * 4 + h;
    float M0 = pM[i0], M1 = pM[i1];
    float L0 = pL[i0], L1 = pL[i1];
    float Msx = fmaxf(M0, M1);
    float r0 = __expf(M0 - Msx), r1 = __expf(M1 - Msx);
    float inv = 1.0f / (r0 * L0 + r1 * L1);
    float4 c0 = f4_load(&pctxw[i0 * Ee + e4]);
    float4 c1 = f4_load(&pctxw[i1 * Ee + e4]);
    float4 res;
    res.x = (r0 * c0.x + r1 * c1.x) * inv;
    res.y = (r0 * c0.y + r1 * c1.y) * inv;
    res.z = (r0 * c0.z + r1 * c1.z) * inv;
    res.w = (r0 * c0.w + r1 * c1.w) * inv;
    f4_store(&cwf[(n * 4 + h) * 132 + e4], res);
  }
  __syncthreads();
  // ctx2[n][k4..k4+3] = bv'[k] + sum_e Wv'[k][e]*cwf[n][h(k)][e]
  {
    const int k4 = lane << 2;
    const int h = lane >> 3;
    float4 a = f4_load(&bvp[k4]);
    for (int ee = 0; ee < 128; ee += 4) {
      float4 cv = f4_load(&cwf[(n * 4 + h) * 132 + ee]);
      float4 w0 = f4_load(&Wvp[(k4 + 0) * Ee + ee]);
      float4 w1 = f4_load(&Wvp[(k4 + 1) * Ee + ee]);
      float4 w2 = f4_load(&Wvp[(k4 + 2) * Ee + ee]);
      float4 w3 = f4_load(&Wvp[(k4 + 3) * Ee + ee]);
      a.x += dot4(w0, cv);
      a.y += dot4(w1, cv);
      a.z += dot4(w2, cv);
      a.w += dot4(w3, cv);
    }
    f4_store(&c2l[n * 132 + k4], a);
  }
  __syncthreads();
  // out[b][gn][e4..] = sbo + sWo @ ctx2
  {
    float4 o = f4_load(&sbo[e4]);
    for (int k0 = 0; k0 < 128; k0 += 4) {
      float4 cv = f4_load(&c2l[n * 132 + k0]);
      float4 w0 = f4_load(&sWo[(e4 + 0) * Ee + k0]);
      float4 w1 = f4_load(&sWo[(e4 + 1) * Ee + k0]);
      float4 w2 = f4_load(&sWo[(e4 + 2) * Ee + k0]);
      float4 w3 = f4_load(&sWo[(e4 + 3) * Ee + k0]);
      o.x += dot4(w0, cv);
      o.y += dot4(w1, cv);
      o.z += dot4(w2, cv);
      o.w += dot4(w3, cv);
    }
    f4_store(&out[((size_t)b * Nn + gn) * Ee + e4], o);
  }
}

// ---------------------------------------------------------------------------
extern "C" void kernel_launch(void* const* d_in, const int* in_sizes, int n_in,
                              void* d_out, int out_size, void* d_ws,
                              size_t ws_size, hipStream_t stream) {
  const float* x = (const float*)d_in[0];
  const int* adj = (const int*)d_in[1];
  const float* tWq = (const float*)d_in[2];
  const float* tbq = (const float*)d_in[3];
  const float* tWk = (const float*)d_in[4];
  const float* tbk = (const float*)d_in[5];
  const float* tWv = (const float*)d_in[6];
  const float* tbv = (const float*)d_in[7];
  const float* tWo = (const float*)d_in[8];
  const float* tbo = (const float*)d_in[9];
  const float* sWq = (const float*)d_in[10];
  const float* sbq = (const float*)d_in[11];
  const float* sWk = (const float*)d_in[12];
  const float* sbk = (const float*)d_in[13];
  const float* sWv = (const float*)d_in[14];
  const float* sbv = (const float*)d_in[15];
  const float* sWo = (const float*)d_in[16];
  const float* sbo = (const float*)d_in[17];
  float* out = (float*)d_out;

  float* ws = (float*)d_ws;
  const size_t ktvt_elems = (size_t)Bb * Nn * Ss * Ee;  // 16,777,216
  float* kt_ws = ws;
  float* vt_ws = kt_ws + ktvt_elems;
  float* qt_ws = vt_ws + ktvt_elems;                       // 524,288
  float* qk2_ws = qt_ws + (size_t)Bb * Nn * Ee;            // 2,097,152
  float* qb2_ws = qk2_ws + (size_t)Bb * Nn * Hh * Ee;      // 16,384
  float* Wkp = qb2_ws + (size_t)Bb * Nn * Hh;
  float* Wvp = Wkp + Ee * Ee;
  float* bkp = Wvp + Ee * Ee;
  float* bvp = bkp + Ee;
  float* pctxw = bvp + Ee;                                 // MS*B*N*4*128
  float* pM = pctxw + (size_t)MS * Bb * Nn * 4 * Ee;       // MS*B*N*4
  float* pL = pM + (size_t)MS * Bb * Nn * 4;

  fuse_weights_kernel<<<dim3(Ee, 2), 128, 0, stream>>>(
      sWk, sbk, sWv, sbv, tWo, tbo, Wkp, bkp, Wvp, bvp);
  qproj_kernel<<<dim3(Bb, 2), 256, 0, stream>>>(
      x, tWq, tbq, sWq, sbq, Wkp, bkp, qt_ws, qk2_ws, qb2_ws);
  ktvt_kernel<<<dim3(Bb, Ss), 256, 0, stream>>>(x, tWk, tbk, tWv, tbv, kt_ws,
                                                vt_ws);
  main_kernel<<<dim3(Bb, 8), 512, 0, stream>>>(
      kt_ws, vt_ws, qt_ws, qk2_ws, qb2_ws, adj, pctxw, pM, pL);
  reduce_kernel<<<dim3(Bb, 8), 256, 0, stream>>>(pctxw, pM, pL, Wvp, bvp, sWo,
                                                 sbo, out);
}